// Round 12
// baseline (70.199 us; speedup 1.0000x reference)
//
#include <hip/hip_runtime.h>
#include <math.h>
#include <utility>

#define K_COMP 64
#define D 32
#define NTRIL 496
#define ICF_COLS 528
#define NPAIR 528            // i<=j pairs
#define NFEAT 560            // 32 linear + 528 pair (constant term in epilogue)
#define NCHUNK 18            // 576 = 18*32 padded features
#define PTS_PER_BLK 32
#define ROWB 1168            // LDS feature-row stride bytes

typedef __attribute__((ext_vector_type(8))) short v8s;
typedef __attribute__((ext_vector_type(4))) float v4f;

__device__ __forceinline__ unsigned short f2bf(float f) {
  unsigned int u = __float_as_uint(f);
  unsigned int r = (u + 0x7FFFu + ((u >> 16) & 1u)) >> 16;
  return (unsigned short)r;
}
__device__ __forceinline__ v8s asv8(int4 v) {
  union { int4 i; v8s s; } u; u.i = v; return u.s;
}

// pair enumeration t -> (i,j), i<=j, i ascending, j from i..31
constexpr int pr_i(int t) { int i = 0; while (t >= D - i) { t -= D - i; ++i; } return i; }
constexpr int pr_j(int t) { int i = 0; while (t >= D - i) { t -= D - i; ++i; } return i + t; }

// feature f: [0,32) = x[f]; [32,560) = x_i*x_j; [560,576) = 0 pad
template<int F> __device__ __forceinline__ float feat(const float (&xr)[D]) {
  if constexpr (F < 32) return xr[F];
  else if constexpr (F < NFEAT) {
    constexpr int t = F - 32, i = pr_i(t), j = pr_j(t);
    return xr[i] * xr[j];
  } else return 0.0f;
}

template<int F0> __device__ __forceinline__ void write4(const float (&xr)[D], char* row) {
  unsigned int d0 = (unsigned int)f2bf(feat<F0+0>(xr)) | ((unsigned int)f2bf(feat<F0+1>(xr)) << 16);
  unsigned int d1 = (unsigned int)f2bf(feat<F0+2>(xr)) | ((unsigned int)f2bf(feat<F0+3>(xr)) << 16);
  *reinterpret_cast<uint2*>(row + (size_t)F0 * 2) = make_uint2(d0, d1);
}
template<int BASE, size_t... Qs> __device__ __forceinline__
void gen72(const float (&xr)[D], char* row, std::index_sequence<Qs...>) {
  (write4<BASE + 4 * (int)Qs>(xr, row), ...);
}

// ------------------- prep: one block per component k -------------------
__global__ __launch_bounds__(64) void gmm_prep(
    const float* __restrict__ alphas, const float* __restrict__ means,
    const float* __restrict__ icf, const float* __restrict__ wg,
    const float* __restrict__ wm,
    uint4* __restrict__ Whi, float* __restrict__ eSa, float* __restrict__ wwk)
{
  int k = blockIdx.x;
  int l = threadIdx.x;
  __shared__ float M[D][D + 1];
  __shared__ float mu[D], b[D], v[D];
  __shared__ float At[NPAIR];
  __shared__ float red[64];

  const float* ick = icf + (size_t)k * ICF_COLS;

  if (l < D) {
    mu[l] = means[k * D + l];
    float q = __expf(ick[l]);
    for (int c = 0; c < D; ++c) {
      float val;
      if (c < l) { int off = c * 31 - c * (c - 1) / 2; val = ick[D + off + (l - c - 1)]; }
      else if (c == l) val = q;
      else val = 0.0f;
      M[l][c] = val;
    }
  }
  __syncthreads();
  if (l < D) {
    float acc = 0.f;
    for (int c = 0; c < D; ++c) acc = fmaf(M[l][c], mu[c], acc);
    b[l] = acc;
  }
  __syncthreads();
  if (l < D) {
    float acc = 0.f;
    for (int r = 0; r < D; ++r) acc = fmaf(M[r][l], b[r], acc);
    v[l] = acc;
  }
  // A[i<=j] = sum_r M[r,i]*M[r,j]; GEMM sign convention (-1/2 diag, -1 off)
  for (int t = l; t < NPAIR; t += 64) {
    int tt = t, i = 0;
    while (tt >= D - i) { tt -= D - i; ++i; }
    int j = i + tt;
    float acc = 0.f;
    for (int r = 0; r < D; ++r) acc = fmaf(M[r][i], M[r][j], acc);
    At[t] = (i == j) ? -0.5f * acc : -acc;
  }
  // sum of squares of all M entries = qsq + lsq
  float part = 0.f;
  for (int e = l; e < D * D; e += 64) {
    float mv = M[e / D][e % D];
    part = fmaf(mv, mv, part);
  }
  red[l] = part;
  __syncthreads();
  for (int st = 32; st > 0; st >>= 1) {
    if (l < st) red[l] += red[l + st];
    __syncthreads();
  }
  if (l == 0) {
    float msq = red[0];
    float sumq = 0.f;
    for (int i = 0; i < D; ++i) sumq += ick[i];
    float bsq = 0.f;
    for (int i = 0; i < D; ++i) bsq = fmaf(b[i], b[i], bsq);
    eSa[k] = alphas[k] + sumq - 0.5f * bsq;   // f32 epilogue constant
    float g = wg[0], mm = wm[0];
    wwk[k] = 0.5f * g * g * msq - mm * sumq;
  }
  __syncthreads();

  // write MFMA A-fragments: slice s = k>>4, row-in-slice = k&15
  int s = k >> 4, krow = k & 15;
  for (int u = l; u < NCHUNK * 4; u += 64) {
    int c = u >> 2, g = u & 3;
    unsigned int hw[4] = {0, 0, 0, 0};
    for (int j2 = 0; j2 < 8; ++j2) {
      int f = c * 32 + g * 8 + j2;
      float wv2;
      if (f < 32) wv2 = v[f];
      else if (f < NFEAT) wv2 = At[f - 32];
      else wv2 = 0.0f;
      hw[j2 >> 1] |= ((unsigned int)f2bf(wv2)) << (16 * (j2 & 1));
    }
    Whi[(s * NCHUNK + c) * 64 + g * 16 + krow] = make_uint4(hw[0], hw[1], hw[2], hw[3]);
  }
}

// ------------------- main: R10 hot path + last-block fused final -------------------
__global__ __launch_bounds__(256, 4) void gmm_main(
    const float* __restrict__ x, const int4* __restrict__ Whi,
    const float* __restrict__ eSa, const float* __restrict__ wwk,
    const float* __restrict__ alphas, const float* __restrict__ wg,
    const float* __restrict__ wm, int N,
    float* __restrict__ partials, unsigned int* __restrict__ counter,
    float* __restrict__ out)
{
  __shared__ __align__(16) char phi[PTS_PER_BLK * ROWB];
  __shared__ float lmm[4][PTS_PER_BLK];
  __shared__ float lss[4][PTS_PER_BLK];
  __shared__ unsigned int isLastS;

  int tid = threadIdx.x;
  int lane = tid & 63;

  // ---- phase 1: feature generation (each thread: one point, 72 features) ----
  {
    int ptl = tid & 31;
    int h = tid >> 5;                 // 0..7
    int n = blockIdx.x * PTS_PER_BLK + ptl;
    int nn = (n < N) ? n : (N - 1);
    float xr[D];
    const float4* xp = reinterpret_cast<const float4*>(x + (size_t)nn * D);
#pragma unroll
    for (int i = 0; i < D / 4; ++i) {
      float4 vv = xp[i];
      xr[4 * i + 0] = vv.x; xr[4 * i + 1] = vv.y; xr[4 * i + 2] = vv.z; xr[4 * i + 3] = vv.w;
    }
    char* row = phi + (size_t)ptl * ROWB;
    switch (h) {
      case 0: gen72<  0>(xr, row, std::make_index_sequence<18>{}); break;
      case 1: gen72< 72>(xr, row, std::make_index_sequence<18>{}); break;
      case 2: gen72<144>(xr, row, std::make_index_sequence<18>{}); break;
      case 3: gen72<216>(xr, row, std::make_index_sequence<18>{}); break;
      case 4: gen72<288>(xr, row, std::make_index_sequence<18>{}); break;
      case 5: gen72<360>(xr, row, std::make_index_sequence<18>{}); break;
      case 6: gen72<432>(xr, row, std::make_index_sequence<18>{}); break;
      case 7: gen72<504>(xr, row, std::make_index_sequence<18>{}); break;
    }
  }
  __syncthreads();

  // ---- phase 2: GEMM inner[k, n] = W @ phi, one k-slice (16 k) per wave ----
  int slice = __builtin_amdgcn_readfirstlane(tid >> 6);
  int g = lane >> 4, n16 = lane & 15;

  v4f acc0 = {0.f, 0.f, 0.f, 0.f};
  v4f acc1 = {0.f, 0.f, 0.f, 0.f};
  const char* brow0 = phi + (size_t)(0 * 16 + n16) * ROWB + g * 16;
  const char* brow1 = phi + (size_t)(1 * 16 + n16) * ROWB + g * 16;
  const int4* wp = Whi + slice * NCHUNK * 64 + lane;

  int4 ah = wp[0];
#pragma unroll
  for (int c = 0; c < NCHUNK; ++c) {
    int4 ah_n;
    if (c + 1 < NCHUNK) ah_n = wp[(c + 1) * 64];
    int4 b0 = *reinterpret_cast<const int4*>(brow0 + c * 64);
    int4 b1 = *reinterpret_cast<const int4*>(brow1 + c * 64);
    v8s ahs = asv8(ah), b0s = asv8(b0), b1s = asv8(b1);
    acc0 = __builtin_amdgcn_mfma_f32_16x16x32_bf16(ahs, b0s, acc0, 0, 0, 0);
    acc1 = __builtin_amdgcn_mfma_f32_16x16x32_bf16(ahs, b1s, acc1, 0, 0, 0);
    ah = ah_n;
  }

  // ---- epilogue: add f32 constant eS[k], per-lane lse over 4 k, merge lane-groups ----
  float4 es = reinterpret_cast<const float4*>(eSa)[slice * 4 + g];
  acc0.x += es.x; acc0.y += es.y; acc0.z += es.z; acc0.w += es.w;
  acc1.x += es.x; acc1.y += es.y; acc1.z += es.z; acc1.w += es.w;

#pragma unroll
  for (int G = 0; G < 2; ++G) {
    v4f a = (G == 0) ? acc0 : acc1;
    float m = fmaxf(fmaxf(a.x, a.y), fmaxf(a.z, a.w));
    float sv = __expf(a.x - m) + __expf(a.y - m) + __expf(a.z - m) + __expf(a.w - m);
#pragma unroll
    for (int off = 16; off <= 32; off <<= 1) {
      float mo = __shfl_xor(m, off);
      float so = __shfl_xor(sv, off);
      float mn = fmaxf(m, mo);
      sv = sv * __expf(m - mn) + so * __expf(mo - mn);
      m = mn;
    }
    if (lane < 16) { lmm[slice][G * 16 + lane] = m; lss[slice][G * 16 + lane] = sv; }
  }
  __syncthreads();

  // ---- in-block merge of the 4 k-slices + block reduction -> 1 float ----
  if (tid < PTS_PER_BLK) {
    float m0 = lmm[0][tid], m1 = lmm[1][tid], m2 = lmm[2][tid], m3 = lmm[3][tid];
    float mm = fmaxf(fmaxf(m0, m1), fmaxf(m2, m3));
    float ss = lss[0][tid] * __expf(m0 - mm) + lss[1][tid] * __expf(m1 - mm)
             + lss[2][tid] * __expf(m2 - mm) + lss[3][tid] * __expf(m3 - mm);
    int n = blockIdx.x * PTS_PER_BLK + tid;
    float lse = (n < N) ? (mm + __logf(ss)) : 0.f;
#pragma unroll
    for (int off = 16; off > 0; off >>= 1) lse += __shfl_down(lse, off);
    if (tid == 0) partials[blockIdx.x] = lse;
  }

  // ---- last-block-done: fused final (cold tail; spills here don't hurt hot loop) ----
  if (tid == 0) {
    __threadfence();
    isLastS = (atomicAdd(counter, 1u) == gridDim.x - 1) ? 1u : 0u;
  }
  __syncthreads();
  if (isLastS == 0) return;
  __threadfence();

  {
    int nblocks = gridDim.x;
    double* sd = reinterpret_cast<double*>(phi);   // reuse dead LDS (phi unused now)
    __shared__ float samax;
    __shared__ double s_slse, s_sa, s_ow;
    volatile const float* vp = partials;

    double acc = 0.0;
    for (int i = tid; i < nblocks; i += 256) acc += (double)vp[i];
    sd[tid] = acc;
    __syncthreads();
    for (int st = 128; st > 0; st >>= 1) {
      if (tid < st) sd[tid] += sd[tid + st];
      __syncthreads();
    }
    if (tid == 0) s_slse = sd[0];
    __syncthreads();

    if (tid < 64) {
      float m = alphas[tid];
#pragma unroll
      for (int off = 32; off > 0; off >>= 1) m = fmaxf(m, __shfl_xor(m, off));
      if (tid == 0) samax = m;
    }
    __syncthreads();

    sd[tid] = (tid < K_COMP) ? exp((double)(alphas[tid] - samax)) : 0.0;
    __syncthreads();
    for (int st = 128; st > 0; st >>= 1) {
      if (tid < st) sd[tid] += sd[tid + st];
      __syncthreads();
    }
    if (tid == 0) s_sa = sd[0];
    __syncthreads();

    sd[tid] = (tid < K_COMP) ? (double)wwk[tid] : 0.0;
    __syncthreads();
    for (int st = 128; st > 0; st >>= 1) {
      if (tid < st) sd[tid] += sd[tid + st];
      __syncthreads();
    }
    if (tid == 0) s_ow = sd[0];
    __syncthreads();

    double nw = (double)D + (double)wm[0] + 1.0;
    sd[tid] = (tid < D) ? lgamma(0.5 * nw + (1.0 - (double)(tid + 1)) * 0.5) : 0.0;
    __syncthreads();
    for (int st = 128; st > 0; st >>= 1) {
      if (tid < st) sd[tid] += sd[tid + st];
      __syncthreads();
    }

    if (tid == 0) {
      double mg = (D * (D - 1) / 4.0) * log(M_PI) + sd[0];
      double lse_a = (double)samax + log(s_sa);
      double gg = (double)wg[0];
      double C = nw * (double)D * log(gg / sqrt(2.0));
      double CONST = -(double)N * D * 0.5 * log(2.0 * M_PI);
      double prior = s_ow - (double)K_COMP * (C - mg);
      out[0] = (float)(CONST + s_slse - (double)N * lse_a + prior);
    }
  }
}

extern "C" void kernel_launch(void* const* d_in, const int* in_sizes, int n_in,
                              void* d_out, int out_size, void* d_ws, size_t ws_size,
                              hipStream_t stream)
{
  const float* alphas = (const float*)d_in[0];
  const float* means  = (const float*)d_in[1];
  const float* icf    = (const float*)d_in[2];
  const float* x      = (const float*)d_in[3];
  const float* wg     = (const float*)d_in[4];
  const float* wm     = (const float*)d_in[5];
  float* out = (float*)d_out;

  int N = in_sizes[3] / D;
  int npblk = (N + PTS_PER_BLK - 1) / PTS_PER_BLK;   // 1563

  char* wsb = (char*)d_ws;
  const size_t WBYTES = (size_t)4 * NCHUNK * 64 * 16; // 73728
  uint4* Whi = (uint4*)wsb;
  float* eSa = (float*)(wsb + WBYTES);
  float* wwk = eSa + K_COMP;
  float* partials = wwk + K_COMP;
  unsigned int* counter = (unsigned int*)(partials + npblk);

  hipMemsetAsync(counter, 0, sizeof(unsigned int), stream);
  gmm_prep<<<K_COMP, 64, 0, stream>>>(alphas, means, icf, wg, wm, Whi, eSa, wwk);
  gmm_main<<<npblk, 256, 0, stream>>>(x, (const int4*)Whi, eSa, wwk, alphas, wg, wm,
                                      N, partials, counter, out);
}

// Round 13
// 48.948 us; speedup vs baseline: 1.4342x; 1.4342x over previous
//
#include <hip/hip_runtime.h>
#include <math.h>

#define K_COMP 64
#define D 32
#define ICF_COLS 528
#define NCH 33               // 32 quadratic chunks (a=0..31) + 1 linear chunk (a=32)
#define SLICES 4

typedef __attribute__((ext_vector_type(8))) short v8s;
typedef __attribute__((ext_vector_type(4))) float v4f;

__device__ __forceinline__ unsigned short f2bf(float f) {
  unsigned int u = __float_as_uint(f);
  unsigned int r = (u + 0x7FFFu + ((u >> 16) & 1u)) >> 16;
  return (unsigned short)r;
}
__device__ __forceinline__ v8s pack8(unsigned a, unsigned b, unsigned c, unsigned d) {
  union { unsigned u[4]; v8s s; } u;
  u.u[0] = a; u.u[1] = b; u.u[2] = c; u.u[3] = d; return u.s;
}
__device__ __forceinline__ v8s asv8(int4 v) {
  union { int4 i; v8s s; } u; u.i = v; return u.s;
}

// ------------------- prep: one block per component k -------------------
// W2 layout: frag[(s*NCH + c)*64 + g*16 + krow] = 8 bf16 coeffs for
// component k = s*16+krow, feature (a=c, b=g*8+j):  c<32 -> -0.5*(M^T M)[c][b],
// c==32 -> v[b] = (M^T M mu)[b].  Constant term goes to eSa (f32 epilogue).
__global__ __launch_bounds__(64) void gmm_prep(
    const float* __restrict__ alphas, const float* __restrict__ means,
    const float* __restrict__ icf, const float* __restrict__ wg,
    const float* __restrict__ wm,
    uint4* __restrict__ W2, float* __restrict__ eSa, float* __restrict__ wwk)
{
  int k = blockIdx.x;
  int l = threadIdx.x;
  __shared__ float M[D][D + 1];
  __shared__ float mu[D], b[D], v[D];
  __shared__ float Afl[D * D];
  __shared__ float red[64];

  const float* ick = icf + (size_t)k * ICF_COLS;

  if (l < D) {
    mu[l] = means[k * D + l];
    float q = __expf(ick[l]);
    for (int c = 0; c < D; ++c) {
      float val;
      if (c < l) { int off = c * 31 - c * (c - 1) / 2; val = ick[D + off + (l - c - 1)]; }
      else if (c == l) val = q;
      else val = 0.0f;
      M[l][c] = val;
    }
  }
  __syncthreads();
  if (l < D) {
    float acc = 0.f;
    for (int c = 0; c < D; ++c) acc = fmaf(M[l][c], mu[c], acc);
    b[l] = acc;
  }
  __syncthreads();
  if (l < D) {
    float acc = 0.f;
    for (int r = 0; r < D; ++r) acc = fmaf(M[r][l], b[r], acc);
    v[l] = acc;
  }
  // full quadratic coefficient matrix with -0.5 folded in
  for (int e = l; e < D * D; e += 64) {
    int a = e >> 5, bb = e & 31;
    float acc = 0.f;
    for (int r = 0; r < D; ++r) acc = fmaf(M[r][a], M[r][bb], acc);
    Afl[e] = -0.5f * acc;
  }
  // sum of squares of all M entries = qsq + lsq
  float part = 0.f;
  for (int e = l; e < D * D; e += 64) {
    float mv = M[e / D][e % D];
    part = fmaf(mv, mv, part);
  }
  red[l] = part;
  __syncthreads();
  for (int st = 32; st > 0; st >>= 1) {
    if (l < st) red[l] += red[l + st];
    __syncthreads();
  }
  if (l == 0) {
    float msq = red[0];
    float sumq = 0.f;
    for (int i = 0; i < D; ++i) sumq += ick[i];
    float bsq = 0.f;
    for (int i = 0; i < D; ++i) bsq = fmaf(b[i], b[i], bsq);
    eSa[k] = alphas[k] + sumq - 0.5f * bsq;   // f32 epilogue constant
    float g = wg[0], mm = wm[0];
    wwk[k] = 0.5f * g * g * msq - mm * sumq;
  }
  __syncthreads();

  // write MFMA A-fragments: slice s = k>>4, row-in-slice = k&15
  int s = k >> 4, krow = k & 15;
  for (int u = l; u < NCH * 4; u += 64) {
    int c = u >> 2, g = u & 3;
    unsigned int hw[4] = {0, 0, 0, 0};
    for (int j2 = 0; j2 < 8; ++j2) {
      int bb = g * 8 + j2;
      float val = (c < D) ? Afl[c * 32 + bb] : v[bb];
      hw[j2 >> 1] |= ((unsigned int)f2bf(val)) << (16 * (j2 & 1));
    }
    W2[(s * NCH + c) * 64 + g * 16 + krow] = make_uint4(hw[0], hw[1], hw[2], hw[3]);
  }
}

// ------------------- main: no LDS, no barriers; wave = 32 points x 64 k -------------------
__global__ __launch_bounds__(256, 4) void gmm_main(
    const float* __restrict__ x, const int4* __restrict__ W2,
    const float* __restrict__ eSa, int N, float* __restrict__ partials)
{
  int tid = threadIdx.x;
  int lane = tid & 63;
  int wv = tid >> 6;
  int w = blockIdx.x * 4 + wv;           // global wave id
  int n16 = lane & 15, g = lane >> 4;

  int pt0 = (2 * w) * 16 + n16;
  int pt1 = (2 * w + 1) * 16 + n16;
  bool pv0 = pt0 < N, pv1 = pt1 < N;
  const float* xr0 = x + (size_t)(pv0 ? pt0 : (N - 1)) * D;
  const float* xr1 = x + (size_t)(pv1 ? pt1 : (N - 1)) * D;

  // per-lane b-range slice of own point's row: xb[j] = x[pt][g*8 + j]
  int bb = g * 8;
  float xb0[8], xb1[8];
  {
    float4 a0 = *reinterpret_cast<const float4*>(xr0 + bb);
    float4 a1 = *reinterpret_cast<const float4*>(xr0 + bb + 4);
    float4 c0 = *reinterpret_cast<const float4*>(xr1 + bb);
    float4 c1 = *reinterpret_cast<const float4*>(xr1 + bb + 4);
    xb0[0]=a0.x; xb0[1]=a0.y; xb0[2]=a0.z; xb0[3]=a0.w;
    xb0[4]=a1.x; xb0[5]=a1.y; xb0[6]=a1.z; xb0[7]=a1.w;
    xb1[0]=c0.x; xb1[1]=c0.y; xb1[2]=c0.z; xb1[3]=c0.w;
    xb1[4]=c1.x; xb1[5]=c1.y; xb1[6]=c1.z; xb1[7]=c1.w;
  }

  const int4* wp = W2 + lane;
  v4f acc[2][SLICES];
#pragma unroll
  for (int t = 0; t < 2; ++t)
#pragma unroll
    for (int s = 0; s < SLICES; ++s) acc[t][s] = (v4f){0.f, 0.f, 0.f, 0.f};

  int4 Ac[SLICES], An[SLICES];
#pragma unroll
  for (int s = 0; s < SLICES; ++s) Ac[s] = wp[(s * NCH) * 64];

#pragma unroll 1
  for (int c = 0; c < NCH; ++c) {
    if (c + 1 < NCH) {
#pragma unroll
      for (int s = 0; s < SLICES; ++s) An[s] = wp[(s * NCH + c + 1) * 64];
    }
    float xa0 = 1.0f, xa1 = 1.0f;
    if (c < D) { xa0 = xr0[c]; xa1 = xr1[c]; }

    unsigned d0[4], d1[4];
#pragma unroll
    for (int q = 0; q < 4; ++q) {
      d0[q] = (unsigned)f2bf(xa0 * xb0[2*q]) | ((unsigned)f2bf(xa0 * xb0[2*q+1]) << 16);
      d1[q] = (unsigned)f2bf(xa1 * xb1[2*q]) | ((unsigned)f2bf(xa1 * xb1[2*q+1]) << 16);
    }
    v8s B0 = pack8(d0[0], d0[1], d0[2], d0[3]);
    v8s B1 = pack8(d1[0], d1[1], d1[2], d1[3]);

#pragma unroll
    for (int s = 0; s < SLICES; ++s) {
      v8s As = asv8(Ac[s]);
      acc[0][s] = __builtin_amdgcn_mfma_f32_16x16x32_bf16(As, B0, acc[0][s], 0, 0, 0);
      acc[1][s] = __builtin_amdgcn_mfma_f32_16x16x32_bf16(As, B1, acc[1][s], 0, 0, 0);
    }
#pragma unroll
    for (int s = 0; s < SLICES; ++s) Ac[s] = An[s];
  }

  // ---- epilogue: +eS, per-lane lse over 16 k, merge g-groups, per-point mask, wave sum ----
  const float4* esp = reinterpret_cast<const float4*>(eSa);
  float tsum[2];
#pragma unroll
  for (int t = 0; t < 2; ++t) {
    float vals[16];
#pragma unroll
    for (int s = 0; s < SLICES; ++s) {
      float4 es = esp[s * 4 + g];
      vals[s*4+0] = acc[t][s].x + es.x;
      vals[s*4+1] = acc[t][s].y + es.y;
      vals[s*4+2] = acc[t][s].z + es.z;
      vals[s*4+3] = acc[t][s].w + es.w;
    }
    float m = vals[0];
#pragma unroll
    for (int i = 1; i < 16; ++i) m = fmaxf(m, vals[i]);
    float sv = 0.f;
#pragma unroll
    for (int i = 0; i < 16; ++i) sv += __expf(vals[i] - m);
#pragma unroll
    for (int off = 16; off <= 32; off <<= 1) {
      float mo = __shfl_xor(m, off);
      float so = __shfl_xor(sv, off);
      float mn = fmaxf(m, mo);
      sv = sv * __expf(m - mn) + so * __expf(mo - mn);
      m = mn;
    }
    bool pv = (t == 0) ? pv0 : pv1;
    float lse = pv ? (m + __logf(sv)) : 0.f;
    // sum the 16 per-point lse values held in lanes 0..15
#pragma unroll
    for (int off = 8; off > 0; off >>= 1) lse += __shfl_down(lse, off);
    tsum[t] = lse;
  }
  if (lane == 0) partials[w] = tsum[0] + tsum[1];
}

// ------------------- final: parallel reductions + parallel special functions -------------------
__global__ __launch_bounds__(256) void gmm_final(
    const float* __restrict__ wwk, const float* __restrict__ partials, int nparts,
    const float* __restrict__ alphas, const float* __restrict__ wg,
    const float* __restrict__ wm, int N, float* __restrict__ out)
{
  int tid = threadIdx.x;
  __shared__ double sd[256];
  __shared__ float samax;
  __shared__ double s_slse, s_sa, s_ow;

  double acc = 0.0;
  for (int i = tid; i < nparts; i += 256) acc += (double)partials[i];
  sd[tid] = acc;
  __syncthreads();
  for (int st = 128; st > 0; st >>= 1) {
    if (tid < st) sd[tid] += sd[tid + st];
    __syncthreads();
  }
  if (tid == 0) s_slse = sd[0];
  __syncthreads();

  if (tid < 64) {
    float m = alphas[tid];
#pragma unroll
    for (int off = 32; off > 0; off >>= 1) m = fmaxf(m, __shfl_xor(m, off));
    if (tid == 0) samax = m;
  }
  __syncthreads();

  sd[tid] = (tid < K_COMP) ? exp((double)(alphas[tid] - samax)) : 0.0;
  __syncthreads();
  for (int st = 128; st > 0; st >>= 1) {
    if (tid < st) sd[tid] += sd[tid + st];
    __syncthreads();
  }
  if (tid == 0) s_sa = sd[0];
  __syncthreads();

  sd[tid] = (tid < K_COMP) ? (double)wwk[tid] : 0.0;
  __syncthreads();
  for (int st = 128; st > 0; st >>= 1) {
    if (tid < st) sd[tid] += sd[tid + st];
    __syncthreads();
  }
  if (tid == 0) s_ow = sd[0];
  __syncthreads();

  double nw = (double)D + (double)wm[0] + 1.0;
  sd[tid] = (tid < D) ? lgamma(0.5 * nw + (1.0 - (double)(tid + 1)) * 0.5) : 0.0;
  __syncthreads();
  for (int st = 128; st > 0; st >>= 1) {
    if (tid < st) sd[tid] += sd[tid + st];
    __syncthreads();
  }

  if (tid == 0) {
    double mg = (D * (D - 1) / 4.0) * log(M_PI) + sd[0];
    double lse_a = (double)samax + log(s_sa);
    double g = (double)wg[0];
    double C = nw * (double)D * log(g / sqrt(2.0));
    double CONST = -(double)N * D * 0.5 * log(2.0 * M_PI);
    double prior = s_ow - (double)K_COMP * (C - mg);
    out[0] = (float)(CONST + s_slse - (double)N * lse_a + prior);
  }
}

extern "C" void kernel_launch(void* const* d_in, const int* in_sizes, int n_in,
                              void* d_out, int out_size, void* d_ws, size_t ws_size,
                              hipStream_t stream)
{
  const float* alphas = (const float*)d_in[0];
  const float* means  = (const float*)d_in[1];
  const float* icf    = (const float*)d_in[2];
  const float* x      = (const float*)d_in[3];
  const float* wg     = (const float*)d_in[4];
  const float* wm     = (const float*)d_in[5];
  float* out = (float*)d_out;

  int N = in_sizes[3] / D;
  int ntiles = (N + 15) / 16;                 // 3125
  int nwaves = (ntiles + 1) / 2;              // 1563
  int nblk   = (nwaves + 3) / 4;              // 391
  int nparts = nblk * 4;                      // 1564 (pad waves write 0)

  char* wsb = (char*)d_ws;
  const size_t W2BYTES = (size_t)SLICES * NCH * 64 * 16;  // 135168
  uint4* W2  = (uint4*)wsb;
  float* eSa = (float*)(wsb + W2BYTES);
  float* wwk = eSa + K_COMP;
  float* partials = wwk + K_COMP;

  gmm_prep<<<K_COMP, 64, 0, stream>>>(alphas, means, icf, wg, wm, W2, eSa, wwk);
  gmm_main<<<nblk, 256, 0, stream>>>(x, (const int4*)W2, eSa, N, partials);
  gmm_final<<<1, 256, 0, stream>>>(wwk, partials, nparts, alphas, wg, wm, N, out);
}

// Round 14
// 41.941 us; speedup vs baseline: 1.6738x; 1.1671x over previous
//
#include <hip/hip_runtime.h>
#include <math.h>
#include <utility>

#define K_COMP 64
#define D 32
#define NTRIL 496
#define ICF_COLS 528
#define NPAIR 528            // i<=j pairs
#define NFEAT 560            // 32 linear + 528 pair (constant term in epilogue)
#define NCHUNK 18            // 576 = 18*32 padded features
#define PTS_PER_BLK 32
#define ROWB 1168            // LDS feature-row stride bytes
#define XSTRIDE 36           // xs row stride in floats (4-aligned, mod-32 = 4)

typedef __attribute__((ext_vector_type(8))) short v8s;
typedef __attribute__((ext_vector_type(4))) float v4f;

__device__ __forceinline__ unsigned short f2bf(float f) {
  unsigned int u = __float_as_uint(f);
  unsigned int r = (u + 0x7FFFu + ((u >> 16) & 1u)) >> 16;
  return (unsigned short)r;
}
__device__ __forceinline__ v8s asv8(int4 v) {
  union { int4 i; v8s s; } u; u.i = v; return u.s;
}

// pair enumeration t -> (i,j), i<=j, i ascending, j from i..31
constexpr int pr_i(int t) { int i = 0; while (t >= D - i) { t -= D - i; ++i; } return i; }
constexpr int pr_j(int t) { int i = 0; while (t >= D - i) { t -= D - i; ++i; } return i + t; }

// feature f: [0,32) = x[f]; [32,560) = x_i*x_j; [560,576) = 0 pad
template<int F> __device__ __forceinline__ float feat(const float (&xr)[D]) {
  if constexpr (F < 32) return xr[F];
  else if constexpr (F < NFEAT) {
    constexpr int t = F - 32, i = pr_i(t), j = pr_j(t);
    return xr[i] * xr[j];
  } else return 0.0f;
}

template<int F0> __device__ __forceinline__ void write4(const float (&xr)[D], char* row) {
  unsigned int d0 = (unsigned int)f2bf(feat<F0+0>(xr)) | ((unsigned int)f2bf(feat<F0+1>(xr)) << 16);
  unsigned int d1 = (unsigned int)f2bf(feat<F0+2>(xr)) | ((unsigned int)f2bf(feat<F0+3>(xr)) << 16);
  *reinterpret_cast<uint2*>(row + (size_t)F0 * 2) = make_uint2(d0, d1);
}
template<int BASE, size_t... Qs> __device__ __forceinline__
void gen72(const float (&xr)[D], char* row, std::index_sequence<Qs...>) {
  (write4<BASE + 4 * (int)Qs>(xr, row), ...);
}

// ------------------- prep: one block per component k -------------------
__global__ __launch_bounds__(64) void gmm_prep(
    const float* __restrict__ alphas, const float* __restrict__ means,
    const float* __restrict__ icf, const float* __restrict__ wg,
    const float* __restrict__ wm,
    uint4* __restrict__ Whi, float* __restrict__ eSa, float* __restrict__ wwk)
{
  int k = blockIdx.x;
  int l = threadIdx.x;
  __shared__ float M[D][D + 1];
  __shared__ float mu[D], b[D], v[D];
  __shared__ float At[NPAIR];
  __shared__ float red[64];

  const float* ick = icf + (size_t)k * ICF_COLS;

  if (l < D) {
    mu[l] = means[k * D + l];
    float q = __expf(ick[l]);
    for (int c = 0; c < D; ++c) {
      float val;
      if (c < l) { int off = c * 31 - c * (c - 1) / 2; val = ick[D + off + (l - c - 1)]; }
      else if (c == l) val = q;
      else val = 0.0f;
      M[l][c] = val;
    }
  }
  __syncthreads();
  if (l < D) {
    float acc = 0.f;
    for (int c = 0; c < D; ++c) acc = fmaf(M[l][c], mu[c], acc);
    b[l] = acc;
  }
  __syncthreads();
  if (l < D) {
    float acc = 0.f;
    for (int r = 0; r < D; ++r) acc = fmaf(M[r][l], b[r], acc);
    v[l] = acc;
  }
  // A[i<=j] = sum_r M[r,i]*M[r,j]; GEMM sign convention (-1/2 diag, -1 off)
  for (int t = l; t < NPAIR; t += 64) {
    int tt = t, i = 0;
    while (tt >= D - i) { tt -= D - i; ++i; }
    int j = i + tt;
    float acc = 0.f;
    for (int r = 0; r < D; ++r) acc = fmaf(M[r][i], M[r][j], acc);
    At[t] = (i == j) ? -0.5f * acc : -acc;
  }
  // sum of squares of all M entries = qsq + lsq
  float part = 0.f;
  for (int e = l; e < D * D; e += 64) {
    float mv = M[e / D][e % D];
    part = fmaf(mv, mv, part);
  }
  red[l] = part;
  __syncthreads();
  for (int st = 32; st > 0; st >>= 1) {
    if (l < st) red[l] += red[l + st];
    __syncthreads();
  }
  if (l == 0) {
    float msq = red[0];
    float sumq = 0.f;
    for (int i = 0; i < D; ++i) sumq += ick[i];
    float bsq = 0.f;
    for (int i = 0; i < D; ++i) bsq = fmaf(b[i], b[i], bsq);
    eSa[k] = alphas[k] + sumq - 0.5f * bsq;   // f32 epilogue constant
    float g = wg[0], mm = wm[0];
    wwk[k] = 0.5f * g * g * msq - mm * sumq;
  }
  __syncthreads();

  // write MFMA A-fragments: slice s = k>>4, row-in-slice = k&15
  int s = k >> 4, krow = k & 15;
  for (int u = l; u < NCHUNK * 4; u += 64) {
    int c = u >> 2, g = u & 3;
    unsigned int hw[4] = {0, 0, 0, 0};
    for (int j2 = 0; j2 < 8; ++j2) {
      int f = c * 32 + g * 8 + j2;
      float wv2;
      if (f < 32) wv2 = v[f];
      else if (f < NFEAT) wv2 = At[f - 32];
      else wv2 = 0.0f;
      hw[j2 >> 1] |= ((unsigned int)f2bf(wv2)) << (16 * (j2 & 1));
    }
    Whi[(s * NCHUNK + c) * 64 + g * 16 + krow] = make_uint4(hw[0], hw[1], hw[2], hw[3]);
  }
}

// ------------------- main: coalesced x staging + feature-gen + GEMM + lse -------------------
__global__ __launch_bounds__(256, 4) void gmm_main(
    const float* __restrict__ x, const int4* __restrict__ Whi,
    const float* __restrict__ eSa, int N, float* __restrict__ partials)
{
  __shared__ __align__(16) char phi[PTS_PER_BLK * ROWB];
  __shared__ __align__(16) float xs[PTS_PER_BLK][XSTRIDE];
  __shared__ float lmm[4][PTS_PER_BLK];
  __shared__ float lss[4][PTS_PER_BLK];

  int tid = threadIdx.x;
  int lane = tid & 63;
  int slice = __builtin_amdgcn_readfirstlane(tid >> 6);
  int g = lane >> 4, n16 = lane & 15;

  // ---- W prefetch: issue first 4 chunks now; latency hides under staging+feature-gen
  const int4* wp = Whi + slice * NCHUNK * 64 + lane;
  int4 Abuf[4];
#pragma unroll
  for (int i = 0; i < 4; ++i) Abuf[i] = wp[i * 64];

  // ---- phase 0: coalesced x-tile load (block tile is one contiguous 4KB span) ----
  {
    size_t fidx = (size_t)blockIdx.x * (PTS_PER_BLK * D) + tid * 4;
    size_t maxf = (size_t)N * D - 4;
    if (fidx > maxf) fidx = maxf;                       // clamp (16B-aligned)
    float4 v = *reinterpret_cast<const float4*>(x + fidx);
    int r = tid >> 3, c = (tid & 7) * 4;
    xs[r][c + 0] = v.x; xs[r][c + 1] = v.y; xs[r][c + 2] = v.z; xs[r][c + 3] = v.w;
  }
  __syncthreads();

  // ---- phase 1: feature generation (each thread: one point, 72 features) ----
  {
    int ptl = tid & 31;
    int h = tid >> 5;                 // 0..7
    float xr[D];
    const float4* xrow = reinterpret_cast<const float4*>(&xs[ptl][0]);
#pragma unroll
    for (int i = 0; i < D / 4; ++i) {
      float4 vv = xrow[i];
      xr[4 * i + 0] = vv.x; xr[4 * i + 1] = vv.y; xr[4 * i + 2] = vv.z; xr[4 * i + 3] = vv.w;
    }
    char* row = phi + (size_t)ptl * ROWB;
    switch (h) {
      case 0: gen72<  0>(xr, row, std::make_index_sequence<18>{}); break;
      case 1: gen72< 72>(xr, row, std::make_index_sequence<18>{}); break;
      case 2: gen72<144>(xr, row, std::make_index_sequence<18>{}); break;
      case 3: gen72<216>(xr, row, std::make_index_sequence<18>{}); break;
      case 4: gen72<288>(xr, row, std::make_index_sequence<18>{}); break;
      case 5: gen72<360>(xr, row, std::make_index_sequence<18>{}); break;
      case 6: gen72<432>(xr, row, std::make_index_sequence<18>{}); break;
      case 7: gen72<504>(xr, row, std::make_index_sequence<18>{}); break;
    }
  }
  __syncthreads();

  // ---- phase 2: GEMM inner[k, n] = W @ phi, one k-slice (16 k) per wave ----
  v4f acc0 = {0.f, 0.f, 0.f, 0.f};
  v4f acc1 = {0.f, 0.f, 0.f, 0.f};
  const char* brow0 = phi + (size_t)(0 * 16 + n16) * ROWB + g * 16;
  const char* brow1 = phi + (size_t)(1 * 16 + n16) * ROWB + g * 16;

#pragma unroll
  for (int c = 0; c < NCHUNK; ++c) {
    int4 cur = Abuf[c & 3];
    if (c + 4 < NCHUNK) Abuf[c & 3] = wp[(c + 4) * 64];   // 4-deep rotating prefetch
    int4 b0 = *reinterpret_cast<const int4*>(brow0 + c * 64);
    int4 b1 = *reinterpret_cast<const int4*>(brow1 + c * 64);
    v8s ahs = asv8(cur), b0s = asv8(b0), b1s = asv8(b1);
    acc0 = __builtin_amdgcn_mfma_f32_16x16x32_bf16(ahs, b0s, acc0, 0, 0, 0);
    acc1 = __builtin_amdgcn_mfma_f32_16x16x32_bf16(ahs, b1s, acc1, 0, 0, 0);
  }

  // ---- epilogue: add f32 constant eS[k], per-lane lse over 4 k, merge lane-groups ----
  float4 es = reinterpret_cast<const float4*>(eSa)[slice * 4 + g];
  acc0.x += es.x; acc0.y += es.y; acc0.z += es.z; acc0.w += es.w;
  acc1.x += es.x; acc1.y += es.y; acc1.z += es.z; acc1.w += es.w;

#pragma unroll
  for (int G = 0; G < 2; ++G) {
    v4f a = (G == 0) ? acc0 : acc1;
    float m = fmaxf(fmaxf(a.x, a.y), fmaxf(a.z, a.w));
    float sv = __expf(a.x - m) + __expf(a.y - m) + __expf(a.z - m) + __expf(a.w - m);
#pragma unroll
    for (int off = 16; off <= 32; off <<= 1) {
      float mo = __shfl_xor(m, off);
      float so = __shfl_xor(sv, off);
      float mn = fmaxf(m, mo);
      sv = sv * __expf(m - mn) + so * __expf(mo - mn);
      m = mn;
    }
    if (lane < 16) { lmm[slice][G * 16 + lane] = m; lss[slice][G * 16 + lane] = sv; }
  }
  __syncthreads();

  // ---- in-block merge of the 4 k-slices + block reduction -> 1 float ----
  if (tid < PTS_PER_BLK) {
    float m0 = lmm[0][tid], m1 = lmm[1][tid], m2 = lmm[2][tid], m3 = lmm[3][tid];
    float mm = fmaxf(fmaxf(m0, m1), fmaxf(m2, m3));
    float ss = lss[0][tid] * __expf(m0 - mm) + lss[1][tid] * __expf(m1 - mm)
             + lss[2][tid] * __expf(m2 - mm) + lss[3][tid] * __expf(m3 - mm);
    int n = blockIdx.x * PTS_PER_BLK + tid;
    float lse = (n < N) ? (mm + __logf(ss)) : 0.f;
#pragma unroll
    for (int off = 16; off > 0; off >>= 1) lse += __shfl_down(lse, off);
    if (tid == 0) partials[blockIdx.x] = lse;
  }
}

// ------------------- final: parallel reductions + parallel special functions -------------------
__global__ __launch_bounds__(256) void gmm_final(
    const float* __restrict__ wwk, const float* __restrict__ partials, int nblocks,
    const float* __restrict__ alphas, const float* __restrict__ wg,
    const float* __restrict__ wm, int N, float* __restrict__ out)
{
  int tid = threadIdx.x;
  __shared__ double sd[256];
  __shared__ float samax;
  __shared__ double s_slse, s_sa, s_ow;

  double acc = 0.0;
  for (int i = tid; i < nblocks; i += 256) acc += (double)partials[i];
  sd[tid] = acc;
  __syncthreads();
  for (int st = 128; st > 0; st >>= 1) {
    if (tid < st) sd[tid] += sd[tid + st];
    __syncthreads();
  }
  if (tid == 0) s_slse = sd[0];
  __syncthreads();

  if (tid < 64) {
    float m = alphas[tid];
#pragma unroll
    for (int off = 32; off > 0; off >>= 1) m = fmaxf(m, __shfl_xor(m, off));
    if (tid == 0) samax = m;
  }
  __syncthreads();

  sd[tid] = (tid < K_COMP) ? exp((double)(alphas[tid] - samax)) : 0.0;
  __syncthreads();
  for (int st = 128; st > 0; st >>= 1) {
    if (tid < st) sd[tid] += sd[tid + st];
    __syncthreads();
  }
  if (tid == 0) s_sa = sd[0];
  __syncthreads();

  sd[tid] = (tid < K_COMP) ? (double)wwk[tid] : 0.0;
  __syncthreads();
  for (int st = 128; st > 0; st >>= 1) {
    if (tid < st) sd[tid] += sd[tid + st];
    __syncthreads();
  }
  if (tid == 0) s_ow = sd[0];
  __syncthreads();

  double nw = (double)D + (double)wm[0] + 1.0;
  sd[tid] = (tid < D) ? lgamma(0.5 * nw + (1.0 - (double)(tid + 1)) * 0.5) : 0.0;
  __syncthreads();
  for (int st = 128; st > 0; st >>= 1) {
    if (tid < st) sd[tid] += sd[tid + st];
    __syncthreads();
  }

  if (tid == 0) {
    double mg = (D * (D - 1) / 4.0) * log(M_PI) + sd[0];
    double lse_a = (double)samax + log(s_sa);
    double g = (double)wg[0];
    double C = nw * (double)D * log(g / sqrt(2.0));
    double CONST = -(double)N * D * 0.5 * log(2.0 * M_PI);
    double prior = s_ow - (double)K_COMP * (C - mg);
    out[0] = (float)(CONST + s_slse - (double)N * lse_a + prior);
  }
}

extern "C" void kernel_launch(void* const* d_in, const int* in_sizes, int n_in,
                              void* d_out, int out_size, void* d_ws, size_t ws_size,
                              hipStream_t stream)
{
  const float* alphas = (const float*)d_in[0];
  const float* means  = (const float*)d_in[1];
  const float* icf    = (const float*)d_in[2];
  const float* x      = (const float*)d_in[3];
  const float* wg     = (const float*)d_in[4];
  const float* wm     = (const float*)d_in[5];
  float* out = (float*)d_out;

  int N = in_sizes[3] / D;
  int npblk = (N + PTS_PER_BLK - 1) / PTS_PER_BLK;   // 1563

  char* wsb = (char*)d_ws;
  const size_t WBYTES = (size_t)4 * NCHUNK * 64 * 16; // 73728
  uint4* Whi = (uint4*)wsb;
  float* eSa = (float*)(wsb + WBYTES);
  float* wwk = eSa + K_COMP;
  float* partials = wwk + K_COMP;

  gmm_prep<<<K_COMP, 64, 0, stream>>>(alphas, means, icf, wg, wm, Whi, eSa, wwk);
  gmm_main<<<npblk, 256, 0, stream>>>(x, (const int4*)Whi, eSa, N, partials);
  gmm_final<<<1, 256, 0, stream>>>(wwk, partials, npblk, alphas, wg, wm, N, out);
}

// Round 15
// 39.953 us; speedup vs baseline: 1.7571x; 1.0498x over previous
//
#include <hip/hip_runtime.h>
#include <hip/hip_bf16.h>
#include <math.h>
#include <utility>

#define K_COMP 64
#define D 32
#define NTRIL 496
#define ICF_COLS 528
#define NPAIR 528            // i<=j pairs
#define NFEAT 560            // 32 linear + 528 pair (constant term in epilogue)
#define NCHUNK 18            // 576 = 18*32 padded features
#define PTS_PER_BLK 32
#define ROWB 1168            // phi row stride bytes
#define XSTRIDE 33           // xs row stride floats: 33 mod 32 = 1 -> conflict-free rows

typedef __attribute__((ext_vector_type(8))) short v8s;
typedef __attribute__((ext_vector_type(4))) float v4f;

__device__ __forceinline__ unsigned short f2bf(float f) {
  unsigned int u = __float_as_uint(f);
  unsigned int r = (u + 0x7FFFu + ((u >> 16) & 1u)) >> 16;
  return (unsigned short)r;
}
__device__ __forceinline__ v8s asv8(int4 v) {
  union { int4 i; v8s s; } u; u.i = v; return u.s;
}

// pair enumeration t -> (i,j), i<=j, i ascending, j from i..31
constexpr int pr_i(int t) { int i = 0; while (t >= D - i) { t -= D - i; ++i; } return i; }
constexpr int pr_j(int t) { int i = 0; while (t >= D - i) { t -= D - i; ++i; } return i + t; }

// feature read DIRECTLY from LDS row (compile-time offsets; no register array)
template<int F> __device__ __forceinline__ float featL(const float* __restrict__ xrow) {
  if constexpr (F < 32) return xrow[F];
  else if constexpr (F < NFEAT) {
    constexpr int t = F - 32, i = pr_i(t), j = pr_j(t);
    return xrow[i] * xrow[j];
  } else return 0.0f;
}

// 4 features -> 2x v_cvt_pk_bf16_f32 -> one 8B LDS write
template<int F0> __device__ __forceinline__ void write4L(const float* __restrict__ xrow, char* row) {
  __hip_bfloat162 pa = __float22bfloat162_rn(make_float2(featL<F0+0>(xrow), featL<F0+1>(xrow)));
  __hip_bfloat162 pb = __float22bfloat162_rn(make_float2(featL<F0+2>(xrow), featL<F0+3>(xrow)));
  union { __hip_bfloat162 h2; unsigned u; } ua, ub;
  ua.h2 = pa; ub.h2 = pb;
  *reinterpret_cast<uint2*>(row + (size_t)F0 * 2) = make_uint2(ua.u, ub.u);
}
template<int BASE, size_t... Qs> __device__ __forceinline__
void gen72(const float* __restrict__ xrow, char* row, std::index_sequence<Qs...>) {
  (write4L<BASE + 4 * (int)Qs>(xrow, row), ...);
}

// ------------------- prep: one block per component k (unchanged, proven) -------------------
__global__ __launch_bounds__(64) void gmm_prep(
    const float* __restrict__ alphas, const float* __restrict__ means,
    const float* __restrict__ icf, const float* __restrict__ wg,
    const float* __restrict__ wm,
    uint4* __restrict__ Whi, float* __restrict__ eSa, float* __restrict__ wwk)
{
  int k = blockIdx.x;
  int l = threadIdx.x;
  __shared__ float M[D][D + 1];
  __shared__ float mu[D], b[D], v[D];
  __shared__ float At[NPAIR];
  __shared__ float red[64];

  const float* ick = icf + (size_t)k * ICF_COLS;

  if (l < D) {
    mu[l] = means[k * D + l];
    float q = __expf(ick[l]);
    for (int c = 0; c < D; ++c) {
      float val;
      if (c < l) { int off = c * 31 - c * (c - 1) / 2; val = ick[D + off + (l - c - 1)]; }
      else if (c == l) val = q;
      else val = 0.0f;
      M[l][c] = val;
    }
  }
  __syncthreads();
  if (l < D) {
    float acc = 0.f;
    for (int c = 0; c < D; ++c) acc = fmaf(M[l][c], mu[c], acc);
    b[l] = acc;
  }
  __syncthreads();
  if (l < D) {
    float acc = 0.f;
    for (int r = 0; r < D; ++r) acc = fmaf(M[r][l], b[r], acc);
    v[l] = acc;
  }
  for (int t = l; t < NPAIR; t += 64) {
    int tt = t, i = 0;
    while (tt >= D - i) { tt -= D - i; ++i; }
    int j = i + tt;
    float acc = 0.f;
    for (int r = 0; r < D; ++r) acc = fmaf(M[r][i], M[r][j], acc);
    At[t] = (i == j) ? -0.5f * acc : -acc;
  }
  float part = 0.f;
  for (int e = l; e < D * D; e += 64) {
    float mv = M[e / D][e % D];
    part = fmaf(mv, mv, part);
  }
  red[l] = part;
  __syncthreads();
  for (int st = 32; st > 0; st >>= 1) {
    if (l < st) red[l] += red[l + st];
    __syncthreads();
  }
  if (l == 0) {
    float msq = red[0];
    float sumq = 0.f;
    for (int i = 0; i < D; ++i) sumq += ick[i];
    float bsq = 0.f;
    for (int i = 0; i < D; ++i) bsq = fmaf(b[i], b[i], bsq);
    eSa[k] = alphas[k] + sumq - 0.5f * bsq;
    float g = wg[0], mm = wm[0];
    wwk[k] = 0.5f * g * g * msq - mm * sumq;
  }
  __syncthreads();

  int s = k >> 4, krow = k & 15;
  for (int u = l; u < NCHUNK * 4; u += 64) {
    int c = u >> 2, g = u & 3;
    unsigned int hw[4] = {0, 0, 0, 0};
    for (int j2 = 0; j2 < 8; ++j2) {
      int f = c * 32 + g * 8 + j2;
      float wv2;
      if (f < 32) wv2 = v[f];
      else if (f < NFEAT) wv2 = At[f - 32];
      else wv2 = 0.0f;
      hw[j2 >> 1] |= ((unsigned int)f2bf(wv2)) << (16 * (j2 & 1));
    }
    Whi[(s * NCHUNK + c) * 64 + g * 16 + krow] = make_uint4(hw[0], hw[1], hw[2], hw[3]);
  }
}

// ------------------- main: LDS-direct feature-gen (low VGPR) + GEMM + lse -------------------
__global__ __launch_bounds__(256, 4) void gmm_main(
    const float* __restrict__ x, const int4* __restrict__ Whi,
    const float* __restrict__ eSa, int N, float* __restrict__ partials)
{
  __shared__ __align__(16) char phi[PTS_PER_BLK * ROWB];
  __shared__ float xs[PTS_PER_BLK][XSTRIDE];
  __shared__ float lmm[4][PTS_PER_BLK];
  __shared__ float lss[4][PTS_PER_BLK];

  int tid = threadIdx.x;
  int lane = tid & 63;
  int slice = __builtin_amdgcn_readfirstlane(tid >> 6);
  int g = lane >> 4, n16 = lane & 15;

  // ---- phase 0: coalesced x-tile load (block tile = contiguous 4KB span) ----
  {
    size_t fidx = (size_t)blockIdx.x * (PTS_PER_BLK * D) + tid * 4;
    size_t maxf = (size_t)N * D - 4;
    if (fidx > maxf) fidx = maxf;
    float4 v = *reinterpret_cast<const float4*>(x + fidx);
    int r = tid >> 3, c = (tid & 7) * 4;
    xs[r][c + 0] = v.x; xs[r][c + 1] = v.y; xs[r][c + 2] = v.z; xs[r][c + 3] = v.w;
  }
  __syncthreads();

  // ---- phase 1: feature generation straight from LDS (no xr[] register array) ----
  {
    int ptl = tid & 31;
    int h = tid >> 5;                 // 0..7
    const float* xrow = &xs[ptl][0];
    char* row = phi + (size_t)ptl * ROWB;
    switch (h) {
      case 0: gen72<  0>(xrow, row, std::make_index_sequence<18>{}); break;
      case 1: gen72< 72>(xrow, row, std::make_index_sequence<18>{}); break;
      case 2: gen72<144>(xrow, row, std::make_index_sequence<18>{}); break;
      case 3: gen72<216>(xrow, row, std::make_index_sequence<18>{}); break;
      case 4: gen72<288>(xrow, row, std::make_index_sequence<18>{}); break;
      case 5: gen72<360>(xrow, row, std::make_index_sequence<18>{}); break;
      case 6: gen72<432>(xrow, row, std::make_index_sequence<18>{}); break;
      case 7: gen72<504>(xrow, row, std::make_index_sequence<18>{}); break;
    }
  }
  __syncthreads();

  // ---- phase 2: GEMM inner[k, n] = W @ phi, one k-slice (16 k) per wave ----
  v4f acc0 = {0.f, 0.f, 0.f, 0.f};
  v4f acc1 = {0.f, 0.f, 0.f, 0.f};
  const char* brow0 = phi + (size_t)(0 * 16 + n16) * ROWB + g * 16;
  const char* brow1 = phi + (size_t)(1 * 16 + n16) * ROWB + g * 16;
  const int4* wp = Whi + slice * NCHUNK * 64 + lane;

  int4 ah = wp[0];
#pragma unroll
  for (int c = 0; c < NCHUNK; ++c) {
    int4 ah_n;
    if (c + 1 < NCHUNK) ah_n = wp[(c + 1) * 64];
    int4 b0 = *reinterpret_cast<const int4*>(brow0 + c * 64);
    int4 b1 = *reinterpret_cast<const int4*>(brow1 + c * 64);
    v8s ahs = asv8(ah), b0s = asv8(b0), b1s = asv8(b1);
    acc0 = __builtin_amdgcn_mfma_f32_16x16x32_bf16(ahs, b0s, acc0, 0, 0, 0);
    acc1 = __builtin_amdgcn_mfma_f32_16x16x32_bf16(ahs, b1s, acc1, 0, 0, 0);
    ah = ah_n;
  }

  // ---- epilogue: add f32 constant eS[k], per-lane lse over 4 k, merge lane-groups ----
  float4 es = reinterpret_cast<const float4*>(eSa)[slice * 4 + g];
  acc0.x += es.x; acc0.y += es.y; acc0.z += es.z; acc0.w += es.w;
  acc1.x += es.x; acc1.y += es.y; acc1.z += es.z; acc1.w += es.w;

#pragma unroll
  for (int G = 0; G < 2; ++G) {
    v4f a = (G == 0) ? acc0 : acc1;
    float m = fmaxf(fmaxf(a.x, a.y), fmaxf(a.z, a.w));
    float sv = __expf(a.x - m) + __expf(a.y - m) + __expf(a.z - m) + __expf(a.w - m);
#pragma unroll
    for (int off = 16; off <= 32; off <<= 1) {
      float mo = __shfl_xor(m, off);
      float so = __shfl_xor(sv, off);
      float mn = fmaxf(m, mo);
      sv = sv * __expf(m - mn) + so * __expf(mo - mn);
      m = mn;
    }
    if (lane < 16) { lmm[slice][G * 16 + lane] = m; lss[slice][G * 16 + lane] = sv; }
  }
  __syncthreads();

  // ---- in-block merge of the 4 k-slices + block reduction -> 1 float ----
  if (tid < PTS_PER_BLK) {
    float m0 = lmm[0][tid], m1 = lmm[1][tid], m2 = lmm[2][tid], m3 = lmm[3][tid];
    float mm = fmaxf(fmaxf(m0, m1), fmaxf(m2, m3));
    float ss = lss[0][tid] * __expf(m0 - mm) + lss[1][tid] * __expf(m1 - mm)
             + lss[2][tid] * __expf(m2 - mm) + lss[3][tid] * __expf(m3 - mm);
    int n = blockIdx.x * PTS_PER_BLK + tid;
    float lse = (n < N) ? (mm + __logf(ss)) : 0.f;
#pragma unroll
    for (int off = 16; off > 0; off >>= 1) lse += __shfl_down(lse, off);
    if (tid == 0) partials[blockIdx.x] = lse;
  }
}

// ------------------- final: parallel reductions + parallel special functions -------------------
__global__ __launch_bounds__(256) void gmm_final(
    const float* __restrict__ wwk, const float* __restrict__ partials, int nblocks,
    const float* __restrict__ alphas, const float* __restrict__ wg,
    const float* __restrict__ wm, int N, float* __restrict__ out)
{
  int tid = threadIdx.x;
  __shared__ double sd[256];
  __shared__ float samax;
  __shared__ double s_slse, s_sa, s_ow;

  double acc = 0.0;
  for (int i = tid; i < nblocks; i += 256) acc += (double)partials[i];
  sd[tid] = acc;
  __syncthreads();
  for (int st = 128; st > 0; st >>= 1) {
    if (tid < st) sd[tid] += sd[tid + st];
    __syncthreads();
  }
  if (tid == 0) s_slse = sd[0];
  __syncthreads();

  if (tid < 64) {
    float m = alphas[tid];
#pragma unroll
    for (int off = 32; off > 0; off >>= 1) m = fmaxf(m, __shfl_xor(m, off));
    if (tid == 0) samax = m;
  }
  __syncthreads();

  sd[tid] = (tid < K_COMP) ? exp((double)(alphas[tid] - samax)) : 0.0;
  __syncthreads();
  for (int st = 128; st > 0; st >>= 1) {
    if (tid < st) sd[tid] += sd[tid + st];
    __syncthreads();
  }
  if (tid == 0) s_sa = sd[0];
  __syncthreads();

  sd[tid] = (tid < K_COMP) ? (double)wwk[tid] : 0.0;
  __syncthreads();
  for (int st = 128; st > 0; st >>= 1) {
    if (tid < st) sd[tid] += sd[tid + st];
    __syncthreads();
  }
  if (tid == 0) s_ow = sd[0];
  __syncthreads();

  double nw = (double)D + (double)wm[0] + 1.0;
  sd[tid] = (tid < D) ? lgamma(0.5 * nw + (1.0 - (double)(tid + 1)) * 0.5) : 0.0;
  __syncthreads();
  for (int st = 128; st > 0; st >>= 1) {
    if (tid < st) sd[tid] += sd[tid + st];
    __syncthreads();
  }

  if (tid == 0) {
    double mg = (D * (D - 1) / 4.0) * log(M_PI) + sd[0];
    double lse_a = (double)samax + log(s_sa);
    double g = (double)wg[0];
    double C = nw * (double)D * log(g / sqrt(2.0));
    double CONST = -(double)N * D * 0.5 * log(2.0 * M_PI);
    double prior = s_ow - (double)K_COMP * (C - mg);
    out[0] = (float)(CONST + s_slse - (double)N * lse_a + prior);
  }
}

extern "C" void kernel_launch(void* const* d_in, const int* in_sizes, int n_in,
                              void* d_out, int out_size, void* d_ws, size_t ws_size,
                              hipStream_t stream)
{
  const float* alphas = (const float*)d_in[0];
  const float* means  = (const float*)d_in[1];
  const float* icf    = (const float*)d_in[2];
  const float* x      = (const float*)d_in[3];
  const float* wg     = (const float*)d_in[4];
  const float* wm     = (const float*)d_in[5];
  float* out = (float*)d_out;

  int N = in_sizes[3] / D;
  int npblk = (N + PTS_PER_BLK - 1) / PTS_PER_BLK;   // 1563

  char* wsb = (char*)d_ws;
  const size_t WBYTES = (size_t)4 * NCHUNK * 64 * 16; // 73728
  uint4* Whi = (uint4*)wsb;
  float* eSa = (float*)(wsb + WBYTES);
  float* wwk = eSa + K_COMP;
  float* partials = wwk + K_COMP;

  gmm_prep<<<K_COMP, 64, 0, stream>>>(alphas, means, icf, wg, wm, Whi, eSa, wwk);
  gmm_main<<<npblk, 256, 0, stream>>>(x, (const int4*)Whi, eSa, N, partials);
  gmm_final<<<1, 256, 0, stream>>>(wwk, partials, npblk, alphas, wg, wm, N, out);
}